// Round 7
// baseline (65.156 us; speedup 1.0000x reference)
//
#include <hip/hip_runtime.h>
#include <hip/hip_fp16.h>

#define T_DIM   1500
#define ROW_F   32000              // floats per row
#define START_T 9                  // max(U-1,1), U=10
#define NB      16384              // N * ctc_beam
#define BLOCK   512
#define CPT     32                 // NB/BLOCK
#define NPAIR   16                 // CPT/2 packed candidate pairs
#define NCHUNK  512                // chunks of 2-3 rows -> 2 blocks/CU
#define NEGBIG  -3.0e38f
#define EOS_ID  1
#define LN2     0.69314718055994531f
#define L2E     1.44269504088896341f

#if __has_builtin(__builtin_amdgcn_exp2f)
__device__ __forceinline__ float fexp2(float x) { return __builtin_amdgcn_exp2f(x); }
#else
__device__ __forceinline__ float fexp2(float x) { return __expf(x * LN2); }
#endif
#if __has_builtin(__builtin_amdgcn_logf)
__device__ __forceinline__ float flog2(float x) { return __builtin_amdgcn_logf(x); }
#else
__device__ __forceinline__ float flog2(float x) { return __logf(x) * L2E; }
#endif

// lgkmcnt(0)-only barrier: orders LDS ops; in-flight global_load_lds DMAs
// (vmcnt) deliberately stay in flight across it.
#define WG_BARRIER() do { \
  asm volatile("s_waitcnt lgkmcnt(0)" ::: "memory"); \
  __builtin_amdgcn_s_barrier(); \
  asm volatile("" ::: "memory"); \
} while (0)

typedef __attribute__((address_space(1))) void* as1_ptr;
typedef __attribute__((address_space(3))) void* as3_ptr;

struct alignas(8) H4p { __half2 a, b; };

// K1: 512 workgroups, chunk q = rows [q*1500>>9, (q+1)*1500>>9) (2-3 rows).
// LDS = 80,480 B -> TWO blocks co-resident per CU; each block's serial
// phases (barrier, reduction, gather) are covered by the sibling block's
// DMA stream. Row granules (256 f32 = one global_load_lds instr per wave)
// stream through a per-wave 2-slot ping-pong with counted vmcnt(1);
// lookahead crosses rows and barriers (never drained except chunk end).
// A row is staged as fp16 probabilities px = exp2(logit*L2E); gather is a
// single fma per candidate with wave-uniform scale 2^(Blocal2 - lse2).
__global__ __launch_bounds__(BLOCK, 4)
void ctc_k1(const float* __restrict__ P, const int* __restrict__ cidx,
            float* __restrict__ Lws, float* __restrict__ Sblank)
{
  __shared__ __align__(16) __half A[32000];      // fp16 px row (64000 B)
  __shared__ __align__(16) float  B[2][8][256];  // per-wave granule ping-pong (16384 B)
  __shared__ float red[12];                      // 8 wave sums + blank logit (x L2E)
  const int tid = threadIdx.x;
  const int w   = tid >> 6;       // wave 0..7
  const int l   = tid & 63;       // lane
  const int q   = blockIdx.x;
  const int t0  = (q * T_DIM) >> 9;
  const int t1  = ((q + 1) * T_DIM) >> 9;
  const int rows = t1 - t0;       // 2 or 3

  // granules per row for this wave: row = 125 granules, wave w owns g==w (mod 8)
  const int NW = (w < 5) ? 16 : 15;

  // candidate indices packed as two u16 A-byte-offsets per VGPR (c*2 < 64000)
  unsigned cidp[NPAIR];
  float acc[CPT];
#pragma unroll
  for (int j = 0; j < NPAIR; ++j) {
    unsigned c0 = (unsigned)cidx[(2*j  )*BLOCK + tid] * 2u;
    unsigned c1 = (unsigned)cidx[(2*j+1)*BLOCK + tid] * 2u;
    cidp[j] = c0 | (c1 << 16);
    acc[2*j] = 0.f; acc[2*j+1] = 0.f;
  }

  // per-wave DMA issue state (flat granule stream across the whole chunk)
  int ir = 0, ii = 0, isl = 0;    // next (row, idx) to issue, issue slot
  int psl = 0;                    // process slot
  auto ISSUE1 = [&]() {
    if (ir < rows) {
      const float* src = P + (long)(t0 + ir) * ROW_F + ((w + (ii << 3)) << 8) + (l << 2);
      __builtin_amdgcn_global_load_lds((as1_ptr)src, (as3_ptr)&B[isl][w][0], 16, 0, 0);
      isl ^= 1;
      if (++ii == NW) { ii = 0; ++ir; }
    }
  };

  float Blocal2 = 0.f;            // chunk-local blank prefix, log2 units

  auto STAGE_ROW = [&](int r) {
    float psum = 0.f;
    const bool lastrow = (r == rows - 1);
#pragma unroll 16
    for (int i = 0; i < 16; ++i) {
      if (i >= NW) break;
      if (lastrow && i == NW - 1) { asm volatile("s_waitcnt vmcnt(0)" ::: "memory"); }
      else                        { asm volatile("s_waitcnt vmcnt(1)" ::: "memory"); }
      const float4 x = *(const float4*)&B[psl][w][l << 2];   // ds_read_b128
      asm volatile("s_waitcnt lgkmcnt(0)" ::: "memory");      // slot free before reissue
      ISSUE1();
      psl ^= 1;
      const int g = w + (i << 3);
      float p0 = fexp2(x.x * L2E), p1 = fexp2(x.y * L2E);
      float p2 = fexp2(x.z * L2E), p3 = fexp2(x.w * L2E);
      psum += (p0 + p1) + (p2 + p3);
      H4p h; h.a = __floats2half2_rn(p0, p1); h.b = __floats2half2_rn(p2, p3);
      *(H4p*)((char*)A + (g << 9) + (l << 3)) = h;            // ds_write_b64
      if (g == 124 && l == 63) red[8] = x.w * L2E;            // exact blank logit (elem 31999)
    }
#pragma unroll
    for (int d = 1; d < 64; d <<= 1) psum += __shfl_xor(psum, d);
    if (l == 0) red[w] = psum;
  };

  auto GATHER = [&](int r) {
    float sum = red[0];
#pragma unroll
    for (int ww = 1; ww < 8; ++ww) sum += red[ww];
    const float lse2 = flog2(sum);
    if (t0 + r >= START_T) {
      const float sc = fexp2(Blocal2 - lse2);   // wave-uniform, no underflow in-chunk
      const char* rb = (const char*)A;
#pragma unroll
      for (int j = 0; j < NPAIR; ++j) {
        unsigned pk = cidp[j];
        float p0 = __half2float(*(const __half*)(rb + (pk & 0xffffu)));
        float p1 = __half2float(*(const __half*)(rb + (pk >> 16)));
        acc[2*j]   = fmaf(sc, p0, acc[2*j]);
        acc[2*j+1] = fmaf(sc, p1, acc[2*j+1]);
      }
    }
    Blocal2 += red[8] - lse2;
  };

  // prologue: 2 granules in flight per wave
  ISSUE1(); ISSUE1();

  for (int r = 0; r < rows; ++r) {
    STAGE_ROW(r);                  // DMA-paced; lookahead crosses into row r+1
    WG_BARRIER();                  // A + red ready for all waves
    GATHER(r);
    WG_BARRIER();                  // all gathers done before A is overwritten
  }

#pragma unroll
  for (int k = 0; k < CPT; ++k) {
    float L = (acc[k] > 0.f) ? flog2(acc[k]) * LN2 : NEGBIG;   // nats
    Lws[(long)q*NB + k*BLOCK + tid] = L;
  }
  if (tid == 0) Sblank[q] = Blocal2 * LN2;
}

#define K3_BLOCK 512

// K3: 256 blocks x 64 candidates; 8 waves split the 512 chunks 8-way.
// Block-scan chunk blank-sums -> base offsets, online logsumexp per part,
// LDS combine, EOS override.
__global__ __launch_bounds__(K3_BLOCK)
void ctc_k3(const float* __restrict__ Lws, const float* __restrict__ Sblank,
            const int* __restrict__ cidx, float* __restrict__ out, int nchunk)
{
  __shared__ float base[513];
  __shared__ float wsum[8];
  __shared__ float pm[8][64], pv[8][64];
  const int tid = threadIdx.x;

  // inclusive block scan of Sblank (nchunk == 512 == blockDim)
  float orig = (tid < nchunk) ? Sblank[tid] : 0.f;
  float x = orig;
#pragma unroll
  for (int d = 1; d < 64; d <<= 1) {
    float y = __shfl_up(x, d);
    if ((tid & 63) >= d) x += y;
  }
  if ((tid & 63) == 63) wsum[tid >> 6] = x;
  __syncthreads();
  {
    const int ww = tid >> 6;
    float pre = 0.f;
    for (int k = 0; k < ww; ++k) pre += wsum[k];
    x += pre;
  }
  base[tid] = x - orig;                       // exclusive prefix: gb[chunk_start-1]
  if (tid == nchunk - 1) base[nchunk] = x;    // total = gb[T-1]
  __syncthreads();

  const int c = tid & 63;          // candidate lane
  const int p = tid >> 6;          // chunk part 0..7
  const int i = blockIdx.x * 64 + c;
  const int c0 = p * 64;
  int c1 = c0 + 64; if (c1 > nchunk) c1 = nchunk;

  float mm = NEGBIG, ssum = 0.f;
#pragma unroll 8
  for (int q2 = c0; q2 < c1; ++q2) {
    float L = Lws[(long)q2*NB + i] + base[q2];   // NEGBIG sentinels contribute 0
    float nm = fmaxf(mm, L);
    ssum = ssum*__expf(mm - nm) + __expf(L - nm);
    mm = nm;
  }
  pm[p][c] = mm; pv[p][c] = ssum;
  __syncthreads();
  if (p == 0) {
#pragma unroll
    for (int pp = 1; pp < 8; ++pp) {
      float om = pm[pp][c], os = pv[pp][c];
      float nm = fmaxf(mm, om);
      ssum = ssum*__expf(mm - nm) + os*__expf(om - nm);
      mm = nm;
    }
    float sc = mm + __logf(ssum);
    out[i] = (cidx[i] == EOS_ID) ? base[nchunk] : sc;
  }
}

extern "C" void kernel_launch(void* const* d_in, const int* in_sizes, int n_in,
                              void* d_out, int out_size, void* d_ws, size_t ws_size,
                              hipStream_t stream)
{
  const float* P    = (const float*)d_in[0];
  const int*   cidx = (const int*)d_in[2];
  float*       out  = (float*)d_out;

  float* Lws    = (float*)d_ws;                 // NCHUNK*NB floats = 33.6 MB
  float* Sblank = Lws + (long)NCHUNK * NB;

  ctc_k1<<<dim3(NCHUNK), dim3(BLOCK), 0, stream>>>(P, cidx, Lws, Sblank);
  ctc_k3<<<dim3(NB / 64), dim3(K3_BLOCK), 0, stream>>>(Lws, Sblank, cidx, out, NCHUNK);
}